// Round 14
// baseline (214.965 us; speedup 1.0000x reference)
//
#include <hip/hip_runtime.h>
#include <hip/hip_bf16.h>

typedef unsigned short u16;

#define B_    4
#define T_    4096
#define C_    512
#define H_    8
#define D_    64
#define WIN_  15
#define PAD_  7
#define M_    (B_*T_)      // 16384 rows
#define NQKV  1536
#define KDIM  512

typedef __bf16 bf16x8 __attribute__((ext_vector_type(8)));
typedef float  f32x4  __attribute__((ext_vector_type(4)));

__device__ __forceinline__ u16 f2bf(float f) {
    union { float f; unsigned int i; } c; c.f = f;
    unsigned int lsb = (c.i >> 16) & 1u;
    c.i += 0x7fffu + lsb;                 // round-to-nearest-even
    return (u16)(c.i >> 16);
}
__device__ __forceinline__ float bf2f(u16 u) {
    union { unsigned int i; float f; } c; c.i = ((unsigned int)u) << 16; return c.f;
}

// ---------------------------------------------------------------------------
// Fused prep: blocks [0,3072) pack fp32 weights -> bf16 transposed Wt[n][k];
// blocks [3072,7168) compute xm = bf16(x * mask[row]).
// ---------------------------------------------------------------------------
#define PACK_BLOCKS 3072
__global__ void prep(const float* __restrict__ Wq, const float* __restrict__ Wkv,
                     const float* __restrict__ Wp,
                     const float* __restrict__ x, const float* __restrict__ mask,
                     u16* __restrict__ Wt_qkv, u16* __restrict__ Wpt,
                     u16* __restrict__ xm)
{
    int bid = blockIdx.x;
    if (bid < PACK_BLOCKS) {
        int idx = bid * 256 + threadIdx.x;   // 0 .. 1536*512-1
        int n = idx >> 9;
        int k = idx & 511;
        float w = (n < 512) ? Wq[k * 512 + n] : Wkv[k * 1024 + (n - 512)];
        Wt_qkv[idx] = f2bf(w);
        if (idx < 512 * 512) Wpt[idx] = f2bf(Wp[k * 512 + n]);
    } else {
        int idx = (bid - PACK_BLOCKS) * 256 + threadIdx.x;  // one per 8 elems
        int e0 = idx * 8;
        float mval = mask[e0 >> 9];
        float4 a = *(const float4*)(x + e0);
        float4 b = *(const float4*)(x + e0 + 4);
        union { uint4 u; u16 s[8]; } o;
        o.s[0] = f2bf(a.x * mval); o.s[1] = f2bf(a.y * mval);
        o.s[2] = f2bf(a.z * mval); o.s[3] = f2bf(a.w * mval);
        o.s[4] = f2bf(b.x * mval); o.s[5] = f2bf(b.y * mval);
        o.s[6] = f2bf(b.z * mval); o.s[7] = f2bf(b.w * mval);
        *(uint4*)(xm + e0) = o.u;
    }
}

// ---------------------------------------------------------------------------
// B-stationary barrier-free GEMM. Block = 256 rows x 64 cols.
// The 64-col x K=512 B panel (64 KB) is staged into LDS ONCE; after a single
// __syncthreads the K-loop has NO barriers: A fragments stream from global
// into registers (wave reads 16 rows x 64 B = 16 full lines, coalesced),
// B frags come from the read-only LDS panel. Compiler emits fine-grained
// vmcnt for the register loads — the R9-R13 structure's per-iteration
// vmcnt(0)+barrier drain (the 46 us plateau) is structurally eliminated.
// LDS 64 KB -> 2 blocks/CU = 8 waves/CU; __launch_bounds__(256,2) caps
// VGPR at 256 (live set ~150; R11's spill trap had cap 170 < live ~230).
// B panel swizzle: slot = (sub & 56) | ((sub ^ col) & 7) — staging writes
// contiguous-permuted (conflict-free), frag reads 2-way (free, m136).
// MFMA as mfma(b, a, acc): lane&15 -> C row, quad*4+reg -> C col; each lane
// owns 4 consecutive C columns -> register-direct vector stores [R9].
// ---------------------------------------------------------------------------
template<bool USE_MASK, bool OUT_F32>
__global__ __launch_bounds__(256, 2) void gemm_bls(
    const u16* __restrict__ A, int lda,
    const float* __restrict__ amask,  // M fp32
    const u16* __restrict__ Bt,       // N x K row-major bf16 (pre-transposed)
    const float* __restrict__ bias0, const float* __restrict__ bias1,
    void* __restrict__ Cc,            // M x N row-major
    int N)
{
    constexpr int KK = 512;
    __shared__ __align__(16) u16 Bs[64 * KK];   // 64 KB

    const int tid  = threadIdx.x;
    const int wave = tid >> 6;
    const int lane = tid & 63;
    const int quad = lane >> 4;
    const int l16  = lane & 15;
    const int row0 = blockIdx.x * 256;
    const int col0 = blockIdx.y * 64;

    // ---- stage B panel once: 4096 chunks of 16B, coalesced ----
    #pragma unroll
    for (int i = 0; i < 16; i++) {
        int c = tid + 256 * i;        // wave-aligned: 64 consecutive c = 1 col
        int col = c >> 6, sub = c & 63;
        uint4 v = *(const uint4*)(Bt + (size_t)(col0 + col) * KK + sub * 8);
        int slot = (sub & 56) | ((sub ^ col) & 7);
        *(uint4*)&Bs[col * KK + slot * 8] = v;
    }
    __syncthreads();                  // the ONLY barrier

    f32x4 acc[4][4] = {};             // [ci][ri]

    const u16* Ar[4];
    #pragma unroll
    for (int ri = 0; ri < 4; ri++)
        Ar[ri] = A + (size_t)(row0 + wave * 64 + ri * 16 + l16) * lda + quad * 8;

    #pragma unroll
    for (int k0 = 0; k0 < KK; k0 += 32) {
        const int subq = (k0 >> 3) + quad;
        bf16x8 a[4], b[4];
        #pragma unroll
        for (int ri = 0; ri < 4; ri++)
            a[ri] = *(const bf16x8*)(Ar[ri] + k0);      // global, no barrier
        #pragma unroll
        for (int ci = 0; ci < 4; ci++) {
            int col = ci * 16 + l16;
            int slot = (subq & 56) | ((subq ^ col) & 7);
            b[ci] = *(const bf16x8*)&Bs[col * KK + slot * 8];
        }
        #pragma unroll
        for (int ci = 0; ci < 4; ci++)
            #pragma unroll
            for (int ri = 0; ri < 4; ri++)
                acc[ci][ri] = __builtin_amdgcn_mfma_f32_16x16x32_bf16(
                    b[ci], a[ri], acc[ci][ri], 0, 0, 0);
    }

    // ---- epilogue: register-direct vectorized stores (R9, conflicts=0) ----
    #pragma unroll
    for (int ri = 0; ri < 4; ri++) {
        const int row = row0 + wave * 64 + ri * 16 + l16;
        float mval = 1.f;
        if (USE_MASK) mval = amask[row];
        #pragma unroll
        for (int ci = 0; ci < 4; ci++) {
            const int colb = col0 + ci * 16 + quad * 4;
            float4 bv = (colb < 512) ? *(const float4*)(bias0 + colb)
                                     : *(const float4*)(bias1 + colb - 512);
            f32x4 v = acc[ci][ri];
            float v0 = v[0] + bv.x, v1 = v[1] + bv.y,
                  v2 = v[2] + bv.z, v3 = v[3] + bv.w;
            if (USE_MASK) { v0 *= mval; v1 *= mval; v2 *= mval; v3 *= mval; }
            if (OUT_F32) {
                float4 o = make_float4(v0, v1, v2, v3);
                *(float4*)((float*)Cc + (size_t)row * N + colb) = o;
            } else {
                union { uint2 u; u16 s[4]; } o;
                o.s[0] = f2bf(v0); o.s[1] = f2bf(v1);
                o.s[2] = f2bf(v2); o.s[3] = f2bf(v3);
                *(uint2*)((u16*)Cc + (size_t)row * N + colb) = o.u;
            }
        }
    }
}

// ---------------------------------------------------------------------------
// Windowed attention: thread-per-(t,h), k/v staged in LDS [jchunk][row].
// Rows outside [0,T) get the bias row. Output in place over the q slot.
// ---------------------------------------------------------------------------
__global__ __launch_bounds__(256) void attn_win2(u16* __restrict__ qkv,
                                                 const float* __restrict__ bkv)
{
    __shared__ uint4 klds[8 * 270];   // [j][row], row = t0-7+row
    __shared__ uint4 vlds[8 * 270];

    const int tid = threadIdx.x;
    const int bid = blockIdx.x;
    const int h  = bid & 7;
    const int b  = (bid >> 3) & 3;
    const int tb = bid >> 5;          // [0,16)
    const int t0 = tb * 256;

    #pragma unroll
    for (int i = 0; i < 9; i++) {
        int idx = i * 256 + tid;
        if (idx < 2160) {
            int row = idx % 270;
            int j   = idx / 270;
            int tt  = t0 - 7 + row;
            uint4 kc, vc;
            if ((unsigned)tt < (unsigned)T_) {
                const u16* g = qkv + ((size_t)b * T_ + tt) * NQKV + 512 + h * 64 + j * 8;
                kc = *(const uint4*)g;
                vc = *(const uint4*)(g + 512);
            } else {
                union { uint4 u; u16 s[8]; } pk, pv;
                #pragma unroll
                for (int e = 0; e < 8; e++) {
                    pk.s[e] = f2bf(bkv[h * 64 + j * 8 + e]);
                    pv.s[e] = f2bf(bkv[512 + h * 64 + j * 8 + e]);
                }
                kc = pk.u; vc = pv.u;
            }
            klds[j * 270 + row] = kc;
            vlds[j * 270 + row] = vc;
        }
    }
    __syncthreads();

    const size_t m = (size_t)b * T_ + t0 + tid;
    u16* qrow = qkv + m * NQKV + h * 64;

    float qf[64];
    #pragma unroll
    for (int j = 0; j < 8; j++) {
        union { uint4 u; u16 s[8]; } t;
        t.u = *(const uint4*)(qrow + j * 8);
        #pragma unroll
        for (int e = 0; e < 8; e++) qf[j * 8 + e] = bf2f(t.s[e]);
    }

    const float scale = 0.042313283f;   // ln(15)/64
    float s[WIN_];
    #pragma unroll
    for (int w = 0; w < WIN_; w++) {
        float acc = 0.f;
        #pragma unroll
        for (int j = 0; j < 8; j++) {
            union { uint4 u; u16 e[8]; } kc;
            kc.u = klds[j * 270 + tid + w];
            #pragma unroll
            for (int e2 = 0; e2 < 8; e2++)
                acc += qf[j * 8 + e2] * bf2f(kc.e[e2]);
        }
        s[w] = acc * scale;
    }

    float mx = s[0];
    #pragma unroll
    for (int w = 1; w < WIN_; w++) mx = fmaxf(mx, s[w]);
    float sum = 0.f;
    #pragma unroll
    for (int w = 0; w < WIN_; w++) { s[w] = __expf(s[w] - mx); sum += s[w]; }
    const float inv = 1.0f / sum;
    #pragma unroll
    for (int w = 0; w < WIN_; w++) s[w] *= inv;

    #pragma unroll
    for (int j = 0; j < 8; j++) {
        float o[8] = {};
        #pragma unroll
        for (int w = 0; w < WIN_; w++) {
            union { uint4 u; u16 e[8]; } vc;
            vc.u = vlds[j * 270 + tid + w];
            #pragma unroll
            for (int e2 = 0; e2 < 8; e2++) o[e2] += s[w] * bf2f(vc.e[e2]);
        }
        union { uint4 u; u16 e[8]; } oc;
        #pragma unroll
        for (int e2 = 0; e2 < 8; e2++) oc.e[e2] = f2bf(o[e2]);
        *(uint4*)(qrow + j * 8) = oc.u;
    }
}

// ---------------------------------------------------------------------------
// Workspace: 66 MiB total.
//   [0, 1.5Mi)    Wt_qkv (1536x512 bf16)
//   [1.5Mi, 2Mi)  Wpt    (512x512 bf16)
//   [2Mi, 18Mi)   xm     (16384x512 bf16)
//   [18Mi, 66Mi)  qkv    (16384x1536 bf16); q section reused for attn output
// ---------------------------------------------------------------------------
extern "C" void kernel_launch(void* const* d_in, const int* in_sizes, int n_in,
                              void* d_out, int out_size, void* d_ws, size_t ws_size,
                              hipStream_t stream)
{
    const float* x    = (const float*)d_in[0];
    const float* mask = (const float*)d_in[1];
    const float* Wq   = (const float*)d_in[2];
    const float* bq   = (const float*)d_in[3];
    const float* Wkv  = (const float*)d_in[4];
    const float* bkv  = (const float*)d_in[5];
    const float* Wp   = (const float*)d_in[6];
    const float* bp   = (const float*)d_in[7];
    float* out = (float*)d_out;

    char* ws = (char*)d_ws;
    u16* Wt_qkv = (u16*)(ws);
    u16* Wpt    = (u16*)(ws + (size_t)(1536 * 1024));
    u16* xm     = (u16*)(ws + (size_t)(2048 * 1024));
    u16* qkv    = (u16*)(ws + (size_t)(18 * 1024 * 1024));

    prep<<<PACK_BLOCKS + (M_ * C_) / (8 * 256), 256, 0, stream>>>(
        Wq, Wkv, Wp, x, mask, Wt_qkv, Wpt, xm);

    dim3 g1(M_ / 256, NQKV / 64);
    gemm_bls<false, false><<<g1, 256, 0, stream>>>(
        xm, KDIM, mask, Wt_qkv, bq, bkv, qkv, NQKV);

    attn_win2<<<(T_ / 256) * B_ * H_, 256, 0, stream>>>(qkv, bkv);

    dim3 g2(M_ / 256, C_ / 64);
    gemm_bls<true, true><<<g2, 256, 0, stream>>>(
        qkv, NQKV, mask, Wpt, bp, nullptr, out, C_);
}